// Round 1
// baseline (436.252 us; speedup 1.0000x reference)
//
#include <hip/hip_runtime.h>
#include <hip/hip_bf16.h>
#include <stdint.h>

// GCN: out = D^-1/2 A D^-1/2 X W + b
// B=4, N=4096, F_IN=F_OUT=128, all fp32 I/O.
// Strategy: fp32 degree pass (HBM-bound), fold d_inv[m] into X (transposed bf16
// copy in ws), then bf16-MFMA GEMM streaming adj once, fused epilogue
// (row-scale by d_inv[n], Z@W via second MFMA, +bias).

#define NROW 4096
#define FDIM 128
#define NBATCH 4

typedef __bf16 bf16x8 __attribute__((ext_vector_type(8)));
typedef float f32x4 __attribute__((ext_vector_type(4)));

// ---------------- kernel 1: degree + d^{-1/2} ----------------
// one block per (b, n) row; 256 threads read 4096 fp32 (16 KB) coalesced.
__global__ __launch_bounds__(256) void k_degree(const float* __restrict__ adj,
                                                float* __restrict__ dinv) {
  const int row = blockIdx.x;  // b*NROW + n
  const float4* arow = (const float4*)(adj + (size_t)row * NROW);
  const int tid = threadIdx.x;
  float s = 0.f;
#pragma unroll
  for (int i = 0; i < 4; ++i) {
    float4 v = arow[tid + i * 256];
    s += (v.x + v.y) + (v.z + v.w);
  }
#pragma unroll
  for (int off = 32; off > 0; off >>= 1) s += __shfl_down(s, off, 64);
  __shared__ float ps[4];
  if ((tid & 63) == 0) ps[tid >> 6] = s;
  __syncthreads();
  if (tid == 0) {
    float d = (ps[0] + ps[1]) + (ps[2] + ps[3]);
    dinv[row] = 1.0f / sqrtf(d + 1e-6f);
  }
}

// ---------------- kernel 2: Xst[b][f][m] = bf16(dinv[b,m] * x[b][m][f]) ----
// transpose 32(m) x 128(f) tiles through LDS (pad 132 words: float4-aligned,
// 2-way max bank aliasing on transposed reads).
__global__ __launch_bounds__(256) void k_xst(const float* __restrict__ x,
                                             const float* __restrict__ dinv,
                                             __hip_bfloat16* __restrict__ xst) {
  const int bid = blockIdx.x;        // 512 blocks
  const int b = bid >> 7;            // 0..3
  const int m0 = (bid & 127) * 32;   // 0..4064
  const int tid = threadIdx.x;
  __shared__ float tile[32 * 132];

  {
    const int ml = tid >> 3;          // 0..31
    const int fl = (tid & 7) * 16;    // 0..112
    const float dv = dinv[b * NROW + m0 + ml];
    const float* gx = x + ((size_t)b * NROW + m0 + ml) * FDIM + fl;
    float* dst = &tile[ml * 132 + fl];
#pragma unroll
    for (int j = 0; j < 16; j += 4) {
      float4 v = *(const float4*)(gx + j);
      v.x *= dv; v.y *= dv; v.z *= dv; v.w *= dv;
      *(float4*)(dst + j) = v;
    }
  }
  __syncthreads();
  {
    const int f = tid >> 1;           // 0..127
    const int mc = (tid & 1) * 16;    // 0 or 16
    union { __hip_bfloat16 h[16]; uint4 v[2]; } tmp;
#pragma unroll
    for (int j = 0; j < 16; ++j)
      tmp.h[j] = __float2bfloat16(tile[(mc + j) * 132 + f]);
    __hip_bfloat16* dst = xst + ((size_t)b * FDIM + f) * NROW + m0 + mc;
    *(uint4*)(dst) = tmp.v[0];
    *(uint4*)(dst + 8) = tmp.v[1];
  }
}

// ---------------- kernel 3: main GEMM + fused epilogue ----------------
// block: 32 rows x 128 cols of Z per batch tile; Kc=64; 4 waves, each wave
// 32 rows x 32 cols (2x2 subtiles of 16x16x32 bf16 MFMA).
#define MT 32
#define KC 64
#define AS_ST 72    // 64+8 bf16: bank rotation 4/row -> conflict-free b128
#define BS_ST 72
#define ZS_ST 136   // 128+8
#define WT_ST 136

__global__ __launch_bounds__(256, 2)
void k_gemm(const float* __restrict__ adj, const __hip_bfloat16* __restrict__ xst,
            const float* __restrict__ dinv, const float* __restrict__ w,
            const float* __restrict__ bias, float* __restrict__ out) {
  __shared__ union {
    struct { __hip_bfloat16 As[MT * AS_ST]; __hip_bfloat16 Bs[FDIM * BS_ST]; } lp;
    struct { __hip_bfloat16 Zs[MT * ZS_ST]; __hip_bfloat16 Wt[FDIM * WT_ST]; } ep;
  } sm;  // max(23040, 43520) = 43520 B -> 2 blocks/CU fits easily
  __shared__ float dinv_s[MT];

  // XCD swizzle: same batch stays on an XCD pair -> Xst slice L2-resident.
  const int bid = blockIdx.x;            // 0..511
  const int xcd = bid & 7;
  const int b = xcd >> 1;                // 0..3
  const int mtile = (bid >> 3) * 2 + (xcd & 1);  // 0..127
  const int row0 = mtile * MT;

  const int tid = threadIdx.x;
  const int lane = tid & 63;
  const int wid = tid >> 6;   // 0..3
  const int l16 = lane & 15;
  const int quad = lane >> 4; // 0..3

  if (tid < MT) dinv_s[tid] = dinv[b * NROW + row0 + tid];

  const float* adj_b = adj + ((size_t)b * NROW + row0) * NROW;
  const __hip_bfloat16* xst_b = xst + (size_t)b * FDIM * NROW;

  f32x4 zero4;
  zero4.x = 0.f; zero4.y = 0.f; zero4.z = 0.f; zero4.w = 0.f;
  f32x4 acc[2][2];
#pragma unroll
  for (int rt = 0; rt < 2; ++rt)
#pragma unroll
    for (int ct = 0; ct < 2; ++ct) acc[rt][ct] = zero4;

  // staging indices
  const int ar = tid >> 3;          // A: row 0..31
  const int ac = (tid & 7) * 8;     // A: k-offset 0..56 (8 fp32 each)
  const int bfr = tid >> 1;         // B: f-row 0..127
  const int bcc = (tid & 1) * 32;   // B: k-offset 0 or 32 (32 bf16 each)
  const float* ga = adj_b + (size_t)ar * NROW + ac;
  const __hip_bfloat16* gb = xst_b + (size_t)bfr * NROW + bcc;

  for (int k0 = 0; k0 < NROW; k0 += KC) {
    {  // stage A tile: fp32 -> bf16, one 16B LDS store per thread
      float4 v0 = *(const float4*)(ga + k0);
      float4 v1 = *(const float4*)(ga + k0 + 4);
      union { __hip_bfloat16 h[8]; uint4 u; } t;
      t.h[0] = __float2bfloat16(v0.x); t.h[1] = __float2bfloat16(v0.y);
      t.h[2] = __float2bfloat16(v0.z); t.h[3] = __float2bfloat16(v0.w);
      t.h[4] = __float2bfloat16(v1.x); t.h[5] = __float2bfloat16(v1.y);
      t.h[6] = __float2bfloat16(v1.z); t.h[7] = __float2bfloat16(v1.w);
      *(uint4*)&sm.lp.As[ar * AS_ST + ac] = t.u;
    }
    {  // stage B tile: straight bf16 copy (already scaled+transposed)
      const __hip_bfloat16* p = gb + k0;
      uint4 u0 = *(const uint4*)(p);
      uint4 u1 = *(const uint4*)(p + 8);
      uint4 u2 = *(const uint4*)(p + 16);
      uint4 u3 = *(const uint4*)(p + 24);
      __hip_bfloat16* q = &sm.lp.Bs[bfr * BS_ST + bcc];
      *(uint4*)(q) = u0;
      *(uint4*)(q + 8) = u1;
      *(uint4*)(q + 16) = u2;
      *(uint4*)(q + 24) = u3;
    }
    __syncthreads();
#pragma unroll
    for (int kk = 0; kk < 2; ++kk) {
      bf16x8 af[2], bfv[2];
#pragma unroll
      for (int rt = 0; rt < 2; ++rt)
        af[rt] = *(const bf16x8*)&sm.lp.As[(rt * 16 + l16) * AS_ST + kk * 32 + quad * 8];
#pragma unroll
      for (int ct = 0; ct < 2; ++ct)
        bfv[ct] = *(const bf16x8*)&sm.lp.Bs[(wid * 32 + ct * 16 + l16) * BS_ST + kk * 32 + quad * 8];
#pragma unroll
      for (int rt = 0; rt < 2; ++rt)
#pragma unroll
        for (int ct = 0; ct < 2; ++ct)
          acc[rt][ct] = __builtin_amdgcn_mfma_f32_16x16x32_bf16(af[rt], bfv[ct], acc[rt][ct], 0, 0, 0);
    }
    __syncthreads();
  }

  // ---- epilogue: Z (scaled by dinv[n]) -> LDS bf16 A-layout; W -> LDS^T bf16
  // C/D layout of 16x16x32: col = lane&15, row = quad*4 + reg.
#pragma unroll
  for (int rt = 0; rt < 2; ++rt)
#pragma unroll
    for (int ct = 0; ct < 2; ++ct)
#pragma unroll
      for (int i = 0; i < 4; ++i) {
        int r = rt * 16 + quad * 4 + i;
        int c = wid * 32 + ct * 16 + l16;
        sm.ep.Zs[r * ZS_ST + c] = __float2bfloat16(acc[rt][ct][i] * dinv_s[r]);
      }
  {  // transpose W[f][o] -> Wt[o][f] (bf16)
    const int f = tid >> 1;
    const int oc = (tid & 1) * 64;
    const float* gw = w + f * FDIM + oc;
#pragma unroll 4
    for (int j = 0; j < 64; j += 4) {
      float4 v = *(const float4*)(gw + j);
      sm.ep.Wt[(oc + j + 0) * WT_ST + f] = __float2bfloat16(v.x);
      sm.ep.Wt[(oc + j + 1) * WT_ST + f] = __float2bfloat16(v.y);
      sm.ep.Wt[(oc + j + 2) * WT_ST + f] = __float2bfloat16(v.z);
      sm.ep.Wt[(oc + j + 3) * WT_ST + f] = __float2bfloat16(v.w);
    }
  }
  __syncthreads();

  f32x4 acc2[2][2];
#pragma unroll
  for (int rt = 0; rt < 2; ++rt)
#pragma unroll
    for (int ct = 0; ct < 2; ++ct) acc2[rt][ct] = zero4;
#pragma unroll
  for (int kk = 0; kk < 4; ++kk) {
    bf16x8 za[2], wb[2];
#pragma unroll
    for (int rt = 0; rt < 2; ++rt)
      za[rt] = *(const bf16x8*)&sm.ep.Zs[(rt * 16 + l16) * ZS_ST + kk * 32 + quad * 8];
#pragma unroll
    for (int ct = 0; ct < 2; ++ct)
      wb[ct] = *(const bf16x8*)&sm.ep.Wt[(wid * 32 + ct * 16 + l16) * WT_ST + kk * 32 + quad * 8];
#pragma unroll
    for (int rt = 0; rt < 2; ++rt)
#pragma unroll
      for (int ct = 0; ct < 2; ++ct)
        acc2[rt][ct] = __builtin_amdgcn_mfma_f32_16x16x32_bf16(za[rt], wb[ct], acc2[rt][ct], 0, 0, 0);
  }

  float bv[2];
  bv[0] = bias[wid * 32 + l16];
  bv[1] = bias[wid * 32 + 16 + l16];
  float* ob = out + ((size_t)b * NROW + row0) * FDIM;
#pragma unroll
  for (int rt = 0; rt < 2; ++rt)
#pragma unroll
    for (int ct = 0; ct < 2; ++ct)
#pragma unroll
      for (int i = 0; i < 4; ++i) {
        int r = rt * 16 + quad * 4 + i;
        int o = wid * 32 + ct * 16 + l16;
        ob[(size_t)r * FDIM + o] = acc2[rt][ct][i] + bv[ct];
      }
}

extern "C" void kernel_launch(void* const* d_in, const int* in_sizes, int n_in,
                              void* d_out, int out_size, void* d_ws, size_t ws_size,
                              hipStream_t stream) {
  const float* x    = (const float*)d_in[0];   // [4,4096,128]
  const float* adj  = (const float*)d_in[1];   // [4,4096,4096]
  const float* w    = (const float*)d_in[2];   // [128,128]
  const float* bias = (const float*)d_in[3];   // [128]
  float* out = (float*)d_out;                  // [4,4096,128]

  float* dinv = (float*)d_ws;                                        // 64 KB
  __hip_bfloat16* xst =
      (__hip_bfloat16*)((char*)d_ws + (size_t)NBATCH * NROW * sizeof(float));  // 4 MiB

  k_degree<<<NBATCH * NROW, 256, 0, stream>>>(adj, dinv);
  k_xst<<<512, 256, 0, stream>>>(x, dinv, xst);
  k_gemm<<<512, 256, 0, stream>>>(adj, xst, dinv, w, bias, out);
}

// Round 2
// 419.778 us; speedup vs baseline: 1.0392x; 1.0392x over previous
//
#include <hip/hip_runtime.h>
#include <hip/hip_bf16.h>
#include <stdint.h>

// GCN: out = D^-1/2 A D^-1/2 X W + b
// B=4, N=4096, F_IN=F_OUT=128, all fp32 I/O.
// v2: k_degree wave-per-row; k_gemm register-prefetch + LDS double-buffer
// (single barrier per K-iter), W fragments direct from global (L2-resident),
// epilogue LDS shrunk to Zs only.

#define NROW 4096
#define FDIM 128
#define NBATCH 4

typedef __bf16 bf16x8 __attribute__((ext_vector_type(8)));
typedef float f32x4 __attribute__((ext_vector_type(4)));

// ---------------- kernel 1: degree + d^{-1/2} ----------------
// one WAVE per row: 64 lanes x 16 float4 = 16 KB row, 16 loads in flight/lane,
// no LDS, no block barrier. grid = 4096 blocks x 4 waves.
__global__ __launch_bounds__(256) void k_degree(const float* __restrict__ adj,
                                                float* __restrict__ dinv) {
  const int row = blockIdx.x * 4 + (threadIdx.x >> 6);  // b*NROW+n
  const int lane = threadIdx.x & 63;
  const float4* arow = (const float4*)(adj + (size_t)row * NROW);
  float s = 0.f;
#pragma unroll
  for (int i = 0; i < 16; ++i) {
    float4 v = arow[lane + i * 64];
    s += (v.x + v.y) + (v.z + v.w);
  }
#pragma unroll
  for (int off = 32; off > 0; off >>= 1) s += __shfl_down(s, off, 64);
  if (lane == 0) dinv[row] = 1.0f / sqrtf(s + 1e-6f);
}

// ---------------- kernel 2: Xst[b][f][m] = bf16(dinv[b,m] * x[b][m][f]) ----
__global__ __launch_bounds__(256) void k_xst(const float* __restrict__ x,
                                             const float* __restrict__ dinv,
                                             __hip_bfloat16* __restrict__ xst) {
  const int bid = blockIdx.x;        // 512 blocks
  const int b = bid >> 7;            // 0..3
  const int m0 = (bid & 127) * 32;   // 0..4064
  const int tid = threadIdx.x;
  __shared__ float tile[32 * 132];

  {
    const int ml = tid >> 3;          // 0..31
    const int fl = (tid & 7) * 16;    // 0..112
    const float dv = dinv[b * NROW + m0 + ml];
    const float* gx = x + ((size_t)b * NROW + m0 + ml) * FDIM + fl;
    float* dst = &tile[ml * 132 + fl];
#pragma unroll
    for (int j = 0; j < 16; j += 4) {
      float4 v = *(const float4*)(gx + j);
      v.x *= dv; v.y *= dv; v.z *= dv; v.w *= dv;
      *(float4*)(dst + j) = v;
    }
  }
  __syncthreads();
  {
    const int f = tid >> 1;           // 0..127
    const int mc = (tid & 1) * 16;    // 0 or 16
    union { __hip_bfloat16 h[16]; uint4 v[2]; } tmp;
#pragma unroll
    for (int j = 0; j < 16; ++j)
      tmp.h[j] = __float2bfloat16(tile[(mc + j) * 132 + f]);
    __hip_bfloat16* dst = xst + ((size_t)b * FDIM + f) * NROW + m0 + mc;
    *(uint4*)(dst) = tmp.v[0];
    *(uint4*)(dst + 8) = tmp.v[1];
  }
}

// ---------------- kernel 3: main GEMM + fused epilogue ----------------
// 32 rows x 128 cols of Z per block; Kc=64; 4 waves, each 32x32 (2x2 of
// 16x16x32 bf16 MFMA). Register-prefetch + LDS dbuf: prefetch loads for
// tile k+1 stay in flight across the single per-iter barrier + MFMA phase.
#define MT 32
#define KC 64
#define AS_ST 72    // 64+8 bf16
#define BS_ST 72
#define ZS_ST 136   // 128+8

__global__ __launch_bounds__(256, 2)
void k_gemm(const float* __restrict__ adj, const __hip_bfloat16* __restrict__ xst,
            const float* __restrict__ dinv, const float* __restrict__ w,
            const float* __restrict__ bias, float* __restrict__ out) {
  __shared__ union {
    struct { __hip_bfloat16 As[2][MT * AS_ST]; __hip_bfloat16 Bs[2][FDIM * BS_ST]; } lp; // 46080 B
    __hip_bfloat16 Zs[MT * ZS_ST];                                                       // 8704 B
  } sm;
  __shared__ float dinv_s[MT];

  // XCD swizzle: same batch stays on an XCD pair -> Xst slice L2-resident.
  const int bid = blockIdx.x;            // 0..511
  const int xcd = bid & 7;
  const int b = xcd >> 1;                // 0..3
  const int mtile = (bid >> 3) * 2 + (xcd & 1);  // 0..127
  const int row0 = mtile * MT;

  const int tid = threadIdx.x;
  const int lane = tid & 63;
  const int wid = tid >> 6;   // 0..3
  const int l16 = lane & 15;
  const int quad = lane >> 4; // 0..3

  if (tid < MT) dinv_s[tid] = dinv[b * NROW + row0 + tid];

  const float* adj_b = adj + ((size_t)b * NROW + row0) * NROW;
  const __hip_bfloat16* xst_b = xst + (size_t)b * FDIM * NROW;

  f32x4 zero4;
  zero4.x = 0.f; zero4.y = 0.f; zero4.z = 0.f; zero4.w = 0.f;
  f32x4 acc[2][2];
#pragma unroll
  for (int rt = 0; rt < 2; ++rt)
#pragma unroll
    for (int ct = 0; ct < 2; ++ct) acc[rt][ct] = zero4;

  // staging indices
  const int ar = tid >> 3;          // A: row 0..31
  const int ac = (tid & 7) * 8;     // A: k-offset 0..56 (8 fp32 each)
  const int bfr = tid >> 1;         // B: f-row 0..127
  const int bcc = (tid & 1) * 32;   // B: k-offset 0 or 32 (32 bf16 each)
  const float* ga = adj_b + (size_t)ar * NROW + ac;
  const __hip_bfloat16* gb = xst_b + (size_t)bfr * NROW + bcc;

  // prologue: prefetch tile 0 into registers
  float4 pa0 = *(const float4*)(ga);
  float4 pa1 = *(const float4*)(ga + 4);
  uint4 pb0 = ((const uint4*)gb)[0];
  uint4 pb1 = ((const uint4*)gb)[1];
  uint4 pb2 = ((const uint4*)gb)[2];
  uint4 pb3 = ((const uint4*)gb)[3];

  int p = 0;
  for (int k0 = 0; k0 < NROW; k0 += KC) {
    {  // drain prefetch regs -> LDS buf[p]
      union { __hip_bfloat16 h[8]; uint4 u; } t;
      t.h[0] = __float2bfloat16(pa0.x); t.h[1] = __float2bfloat16(pa0.y);
      t.h[2] = __float2bfloat16(pa0.z); t.h[3] = __float2bfloat16(pa0.w);
      t.h[4] = __float2bfloat16(pa1.x); t.h[5] = __float2bfloat16(pa1.y);
      t.h[6] = __float2bfloat16(pa1.z); t.h[7] = __float2bfloat16(pa1.w);
      *(uint4*)&sm.lp.As[p][ar * AS_ST + ac] = t.u;
      __hip_bfloat16* q = &sm.lp.Bs[p][bfr * BS_ST + bcc];
      *(uint4*)(q) = pb0;
      *(uint4*)(q + 8) = pb1;
      *(uint4*)(q + 16) = pb2;
      *(uint4*)(q + 24) = pb3;
    }
    if (k0 + KC < NROW) {  // issue next-tile loads; they fly across barrier+MFMA
      const float* gan = ga + k0 + KC;
      pa0 = *(const float4*)(gan);
      pa1 = *(const float4*)(gan + 4);
      const __hip_bfloat16* gbn = gb + k0 + KC;
      pb0 = ((const uint4*)gbn)[0];
      pb1 = ((const uint4*)gbn)[1];
      pb2 = ((const uint4*)gbn)[2];
      pb3 = ((const uint4*)gbn)[3];
    }
    __syncthreads();   // single barrier per iter (dbuf makes 2nd unnecessary)
#pragma unroll
    for (int kk = 0; kk < 2; ++kk) {
      bf16x8 af[2], bfv[2];
#pragma unroll
      for (int rt = 0; rt < 2; ++rt)
        af[rt] = *(const bf16x8*)&sm.lp.As[p][(rt * 16 + l16) * AS_ST + kk * 32 + quad * 8];
#pragma unroll
      for (int ct = 0; ct < 2; ++ct)
        bfv[ct] = *(const bf16x8*)&sm.lp.Bs[p][(wid * 32 + ct * 16 + l16) * BS_ST + kk * 32 + quad * 8];
#pragma unroll
      for (int rt = 0; rt < 2; ++rt)
#pragma unroll
        for (int ct = 0; ct < 2; ++ct)
          acc[rt][ct] = __builtin_amdgcn_mfma_f32_16x16x32_bf16(af[rt], bfv[ct], acc[rt][ct], 0, 0, 0);
    }
    p ^= 1;
  }
  __syncthreads();  // all MFMA reads done before LDS reuse

  // ---- epilogue: Z (scaled by dinv[n]) -> LDS bf16 A-layout.
  // C/D layout of 16x16x32: col = lane&15, row = quad*4 + reg.
#pragma unroll
  for (int rt = 0; rt < 2; ++rt)
#pragma unroll
    for (int ct = 0; ct < 2; ++ct)
#pragma unroll
      for (int i = 0; i < 4; ++i) {
        int r = rt * 16 + quad * 4 + i;
        int c = wid * 32 + ct * 16 + l16;
        sm.Zs[r * ZS_ST + c] = __float2bfloat16(acc[rt][ct][i] * dinv_s[r]);
      }
  __syncthreads();

  // second GEMM: Z @ W. W fragments straight from global (64 KB, L2-resident):
  // B-frag element = W[f = kk*32+quad*8+j][o = wid*32+ct*16+l16], lanes
  // consecutive in o -> coalesced 64 B per 16 lanes.
  f32x4 acc2[2][2];
#pragma unroll
  for (int rt = 0; rt < 2; ++rt)
#pragma unroll
    for (int ct = 0; ct < 2; ++ct) acc2[rt][ct] = zero4;
#pragma unroll
  for (int kk = 0; kk < 4; ++kk) {
    bf16x8 za[2], wb[2];
#pragma unroll
    for (int rt = 0; rt < 2; ++rt)
      za[rt] = *(const bf16x8*)&sm.Zs[(rt * 16 + l16) * ZS_ST + kk * 32 + quad * 8];
#pragma unroll
    for (int ct = 0; ct < 2; ++ct) {
      const int o = wid * 32 + ct * 16 + l16;
      const float* gw = w + (kk * 32 + quad * 8) * FDIM + o;
      union { __hip_bfloat16 h[8]; bf16x8 v; } tw;
#pragma unroll
      for (int j = 0; j < 8; ++j)
        tw.h[j] = __float2bfloat16(gw[j * FDIM]);
      wb[ct] = tw.v;
    }
#pragma unroll
    for (int rt = 0; rt < 2; ++rt)
#pragma unroll
      for (int ct = 0; ct < 2; ++ct)
        acc2[rt][ct] = __builtin_amdgcn_mfma_f32_16x16x32_bf16(za[rt], wb[ct], acc2[rt][ct], 0, 0, 0);
  }

  float bv[2];
  bv[0] = bias[wid * 32 + l16];
  bv[1] = bias[wid * 32 + 16 + l16];
  float* ob = out + ((size_t)b * NROW + row0) * FDIM;
#pragma unroll
  for (int rt = 0; rt < 2; ++rt)
#pragma unroll
    for (int ct = 0; ct < 2; ++ct)
#pragma unroll
      for (int i = 0; i < 4; ++i) {
        int r = rt * 16 + quad * 4 + i;
        int o = wid * 32 + ct * 16 + l16;
        ob[(size_t)r * FDIM + o] = acc2[rt][ct][i] + bv[ct];
      }
}

extern "C" void kernel_launch(void* const* d_in, const int* in_sizes, int n_in,
                              void* d_out, int out_size, void* d_ws, size_t ws_size,
                              hipStream_t stream) {
  const float* x    = (const float*)d_in[0];   // [4,4096,128]
  const float* adj  = (const float*)d_in[1];   // [4,4096,4096]
  const float* w    = (const float*)d_in[2];   // [128,128]
  const float* bias = (const float*)d_in[3];   // [128]
  float* out = (float*)d_out;                  // [4,4096,128]

  float* dinv = (float*)d_ws;                                        // 64 KB
  __hip_bfloat16* xst =
      (__hip_bfloat16*)((char*)d_ws + (size_t)NBATCH * NROW * sizeof(float));  // 4 MiB

  k_degree<<<NBATCH * NROW / 4, 256, 0, stream>>>(adj, dinv);
  k_xst<<<512, 256, 0, stream>>>(x, dinv, xst);
  k_gemm<<<512, 256, 0, stream>>>(adj, xst, dinv, w, bias, out);
}